// Round 8
// baseline (269.108 us; speedup 1.0000x reference)
//
#include <hip/hip_runtime.h>
#include <hip/hip_bf16.h>

// SAGEConv(mean) via CSR (XCD-privatized histogram, rank-trick atomic-free
// fill) + bf16 gather + MFMA fused [mean|x]@[Wl;Wr]^T + L2norm + ReLU +
// BN-partials + stats-reduce + BN-fold FC.  N=100000, E=1200000, F=H=64, C=16.
//
// ws layout (4B words):
//   [cnt: K*N][deg: N][rowptr: N+1][colv: E][rank: E][mh: N*32 bf16 mean->h]
//   [pstats: fblocks*128][stats: 128][bsum: 256][xbf: N*32 bf16 x (optional)]
// Lessons: R4 — same-address f32 atomics cross-XCD = ~600us. R5 — per-edge
// cursor atomics = 99us. R7 — hist atomics ping-pong deg lines across XCDs
// (42MB WRITE_SIZE for a 400KB array); K=8 copies selected by blockIdx%8
// keep each copy XCD-local (round-robin dispatch), killing line migration.

typedef __attribute__((ext_vector_type(8))) short short8;   // 8 bf16
typedef __attribute__((ext_vector_type(4))) float f32x4;

__device__ __forceinline__ unsigned short f2bf(float f) {
    unsigned int u = __builtin_bit_cast(unsigned int, f);
    u += 0x7FFFu + ((u >> 16) & 1u);
    return (unsigned short)(u >> 16);
}
__device__ __forceinline__ float bf2f(unsigned short s) {
    return __builtin_bit_cast(float, ((unsigned int)s) << 16);
}

// ---------------- degree hist (K privatized copies) + per-edge rank in copy
__global__ __launch_bounds__(256) void k_histrank(const int* __restrict__ eidx,
                                                  int* __restrict__ cnt,
                                                  int* __restrict__ rank,
                                                  int E, int N, int K) {
    int t = blockIdx.x * 256 + threadIdx.x;
    if (t < E) {
        int* c = cnt + (size_t)(blockIdx.x % K) * N;
        rank[t] = atomicAdd(&c[eidx[E + t]], 1);
    }
}

// -------------- per-node: exclusive prefix over the K copies (in-place) + deg
__global__ __launch_bounds__(256) void k_deg(int* __restrict__ cnt,
                                             int* __restrict__ deg, int N, int K) {
    int n = blockIdx.x * 256 + threadIdx.x;
    if (n >= N) return;
    int run = 0;
    for (int j = 0; j < K; ++j) {
        int v = cnt[(size_t)j * N + n];
        cnt[(size_t)j * N + n] = run;
        run += v;
    }
    deg[n] = run;
}

// ------------------------------------------- scan level 1: per-block local scan
__global__ __launch_bounds__(256) void k_scan1(const int* __restrict__ deg,
                                               int* __restrict__ rowptr,
                                               int* __restrict__ bsum, int N) {
    __shared__ int swave[4];
    const int tid = threadIdx.x;
    const int base = blockIdx.x * 1024 + tid * 4;
    int v0 = (base + 0 < N) ? deg[base + 0] : 0;
    int v1 = (base + 1 < N) ? deg[base + 1] : 0;
    int v2 = (base + 2 < N) ? deg[base + 2] : 0;
    int v3 = (base + 3 < N) ? deg[base + 3] : 0;
    int tsum = v0 + v1 + v2 + v3;
    const int lane = tid & 63, wid = tid >> 6;
    int s = tsum;
#pragma unroll
    for (int off = 1; off < 64; off <<= 1) {
        int t = __shfl_up(s, off);
        if (lane >= off) s += t;
    }
    if (lane == 63) swave[wid] = s;
    __syncthreads();
    if (tid == 0) {
        int a = 0;
#pragma unroll
        for (int w = 0; w < 4; ++w) { int t = swave[w]; swave[w] = a; a += t; }
    }
    __syncthreads();
    int run = s - tsum + swave[wid];
    if (base + 0 < N) rowptr[base + 0] = run; run += v0;
    if (base + 1 < N) rowptr[base + 1] = run; run += v1;
    if (base + 2 < N) rowptr[base + 2] = run; run += v2;
    if (base + 3 < N) rowptr[base + 3] = run;
    if (tid == 255) bsum[blockIdx.x] = swave[3] + s;
}

// ------------------------------------------- scan level 2: scan the block sums
__global__ __launch_bounds__(256) void k_scan2(int* __restrict__ bsum, int nblk) {
    __shared__ int s[256];
    int tid = threadIdx.x;
    int v = (tid < nblk) ? bsum[tid] : 0;
    s[tid] = v;
    __syncthreads();
    for (int off = 1; off < 256; off <<= 1) {
        int t = (tid >= off) ? s[tid - off] : 0;
        __syncthreads();
        s[tid] += t;
        __syncthreads();
    }
    if (tid < nblk) bsum[tid] = s[tid] - v;
}

// ------------------------------------------- scan level 3: add block offsets
__global__ __launch_bounds__(256) void k_scan3(int* __restrict__ rowptr,
                                               const int* __restrict__ bsum,
                                               int N, int E) {
    const int tid = threadIdx.x;
    const int base = blockIdx.x * 1024 + tid * 4;
    const int off = bsum[blockIdx.x];
#pragma unroll
    for (int p = 0; p < 4; ++p) {
        int i = base + p;
        if (i < N) rowptr[i] += off;
    }
    if (blockIdx.x == 0 && tid == 0) rowptr[N] = E;
}

// ------------------- CSR fill, atomic-free: pos = rowptr + copy-prefix + rank
__global__ __launch_bounds__(256) void k_fill(const int* __restrict__ eidx,
                                              const int* __restrict__ rowptr,
                                              const int* __restrict__ cnt,
                                              const int* __restrict__ rank,
                                              int* __restrict__ colv,
                                              int E, int N, int K) {
    int t = blockIdx.x * 256 + threadIdx.x;
    if (t < E) {
        int d = eidx[E + t];
        int k = blockIdx.x % K;
        colv[rowptr[d] + cnt[(size_t)k * N + d] + rank[t]] = eidx[t];
    }
}

// ---------------------------------------------------------------- x -> bf16
__global__ __launch_bounds__(256) void k_xcast(const float4* __restrict__ x4,
                                               ushort4* __restrict__ xbf, int n4) {
    int t = blockIdx.x * 256 + threadIdx.x;
    if (t < n4) {
        float4 v = x4[t];
        xbf[t] = make_ushort4(f2bf(v.x), f2bf(v.y), f2bf(v.z), f2bf(v.w));
    }
}

// ------------------------- gather-mean (bf16 x): 16 lanes/node, full occupancy
__global__ __launch_bounds__(256) void k_gather_bf(
        const ushort4* __restrict__ xbf, const int* __restrict__ rowptr,
        const int* __restrict__ colv, ushort4* __restrict__ mh, int N) {
    int t = blockIdx.x * 256 + threadIdx.x;
    int n = t >> 4;
    int l = t & 15;
    if (n >= N) return;
    int b = rowptr[n], e = rowptr[n + 1];
    float ax = 0.f, ay = 0.f, az = 0.f, aw = 0.f;
    int p = b;
    for (; p + 4 <= e; p += 4) {
        int s0 = colv[p], s1 = colv[p + 1], s2 = colv[p + 2], s3 = colv[p + 3];
        ushort4 v0 = xbf[(size_t)s0 * 16 + l];
        ushort4 v1 = xbf[(size_t)s1 * 16 + l];
        ushort4 v2 = xbf[(size_t)s2 * 16 + l];
        ushort4 v3 = xbf[(size_t)s3 * 16 + l];
        ax += (bf2f(v0.x) + bf2f(v1.x)) + (bf2f(v2.x) + bf2f(v3.x));
        ay += (bf2f(v0.y) + bf2f(v1.y)) + (bf2f(v2.y) + bf2f(v3.y));
        az += (bf2f(v0.z) + bf2f(v1.z)) + (bf2f(v2.z) + bf2f(v3.z));
        aw += (bf2f(v0.w) + bf2f(v1.w)) + (bf2f(v2.w) + bf2f(v3.w));
    }
    for (; p < e; ++p) {
        int s0 = colv[p];
        ushort4 v0 = xbf[(size_t)s0 * 16 + l];
        ax += bf2f(v0.x); ay += bf2f(v0.y); az += bf2f(v0.z); aw += bf2f(v0.w);
    }
    float inv = 1.0f / fmaxf((float)(e - b), 1.0f);
    mh[(size_t)n * 16 + l] = make_ushort4(f2bf(ax * inv), f2bf(ay * inv),
                                          f2bf(az * inv), f2bf(aw * inv));
}

// ------------------------- gather-mean (f32 x fallback, if ws too small)
__global__ __launch_bounds__(256) void k_gather_f32(
        const float4* __restrict__ x4, const int* __restrict__ rowptr,
        const int* __restrict__ colv, ushort4* __restrict__ mh, int N) {
    int t = blockIdx.x * 256 + threadIdx.x;
    int n = t >> 4;
    int l = t & 15;
    if (n >= N) return;
    int b = rowptr[n], e = rowptr[n + 1];
    float ax = 0.f, ay = 0.f, az = 0.f, aw = 0.f;
    int p = b;
    for (; p + 4 <= e; p += 4) {
        int s0 = colv[p], s1 = colv[p + 1], s2 = colv[p + 2], s3 = colv[p + 3];
        float4 v0 = x4[(size_t)s0 * 16 + l];
        float4 v1 = x4[(size_t)s1 * 16 + l];
        float4 v2 = x4[(size_t)s2 * 16 + l];
        float4 v3 = x4[(size_t)s3 * 16 + l];
        ax += (v0.x + v1.x) + (v2.x + v3.x);
        ay += (v0.y + v1.y) + (v2.y + v3.y);
        az += (v0.z + v1.z) + (v2.z + v3.z);
        aw += (v0.w + v1.w) + (v2.w + v3.w);
    }
    for (; p < e; ++p) {
        int s0 = colv[p];
        float4 v0 = x4[(size_t)s0 * 16 + l];
        ax += v0.x; ay += v0.y; az += v0.z; aw += v0.w;
    }
    float inv = 1.0f / fmaxf((float)(e - b), 1.0f);
    mh[(size_t)n * 16 + l] = make_ushort4(f2bf(ax * inv), f2bf(ay * inv),
                                          f2bf(az * inv), f2bf(aw * inv));
}

// --------- fused MFMA: [mean|x]@[Wl;Wr]^T + bl, L2norm, ReLU, BN partials.
__global__ __launch_bounds__(256) void k_fused(
        const float* __restrict__ x,
        const float* __restrict__ Wl, const float* __restrict__ bl,
        const float* __restrict__ Wr,
        unsigned short* __restrict__ mh,   // in: bf16 mean; out: bf16 h
        float* __restrict__ pstats, int N) {
    __shared__ float sRed[4][128];

    const int tid = threadIdx.x;
    const int wid = tid >> 6;
    const int lane = tid & 63;
    const int l15 = lane & 15;
    const int quad = lane >> 4;
    const int tbase = blockIdx.x * 64 + wid * 16;

    short8 bfrag[4][4];
#pragma unroll
    for (int c = 0; c < 4; ++c) {
#pragma unroll
        for (int f = 0; f < 4; ++f) {
            const int n = f * 16 + l15;
            const float* wsrc = (c < 2)
                ? (Wl + (size_t)n * 64 + c * 32 + quad * 8)
                : (Wr + (size_t)n * 64 + (c - 2) * 32 + quad * 8);
            float4 w0 = *(const float4*)wsrc;
            float4 w1 = *(const float4*)(wsrc + 4);
            union { short8 v; unsigned short u[8]; } pk;
            pk.u[0] = f2bf(w0.x); pk.u[1] = f2bf(w0.y);
            pk.u[2] = f2bf(w0.z); pk.u[3] = f2bf(w0.w);
            pk.u[4] = f2bf(w1.x); pk.u[5] = f2bf(w1.y);
            pk.u[6] = f2bf(w1.z); pk.u[7] = f2bf(w1.w);
            bfrag[c][f] = pk.v;
        }
    }

    const int mrow = tbase + l15;
    const int mld = (mrow < N) ? mrow : (N - 1);
    f32x4 acc[4] = {{0.f, 0.f, 0.f, 0.f}, {0.f, 0.f, 0.f, 0.f},
                    {0.f, 0.f, 0.f, 0.f}, {0.f, 0.f, 0.f, 0.f}};
#pragma unroll
    for (int c = 0; c < 2; ++c) {
        short8 a = *(const short8*)(mh + (size_t)mld * 64 + c * 32 + quad * 8);
#pragma unroll
        for (int f = 0; f < 4; ++f)
            acc[f] = __builtin_amdgcn_mfma_f32_16x16x32_bf16(a, bfrag[c][f], acc[f], 0, 0, 0);
    }
#pragma unroll
    for (int c = 2; c < 4; ++c) {
        const float* xp = x + (size_t)mld * 64 + (c - 2) * 32 + quad * 8;
        float4 a0 = *(const float4*)xp;
        float4 a1 = *(const float4*)(xp + 4);
        union { short8 v; unsigned short u[8]; } pk;
        pk.u[0] = f2bf(a0.x); pk.u[1] = f2bf(a0.y);
        pk.u[2] = f2bf(a0.z); pk.u[3] = f2bf(a0.w);
        pk.u[4] = f2bf(a1.x); pk.u[5] = f2bf(a1.y);
        pk.u[6] = f2bf(a1.z); pk.u[7] = f2bf(a1.w);
#pragma unroll
        for (int f = 0; f < 4; ++f)
            acc[f] = __builtin_amdgcn_mfma_f32_16x16x32_bf16(pk.v, bfrag[c][f], acc[f], 0, 0, 0);
    }

    float blv[4];
#pragma unroll
    for (int f = 0; f < 4; ++f) blv[f] = bl[f * 16 + l15];

    float psum[4] = {0.f, 0.f, 0.f, 0.f};
    float psq[4] = {0.f, 0.f, 0.f, 0.f};
#pragma unroll
    for (int reg = 0; reg < 4; ++reg) {
        const int node = tbase + quad * 4 + reg;
        float hv[4];
        float ss = 0.f;
#pragma unroll
        for (int f = 0; f < 4; ++f) {
            hv[f] = acc[f][reg] + blv[f];
            ss += hv[f] * hv[f];
        }
        ss += __shfl_xor(ss, 1);
        ss += __shfl_xor(ss, 2);
        ss += __shfl_xor(ss, 4);
        ss += __shfl_xor(ss, 8);
        float sc = 1.0f / fmaxf(sqrtf(ss), 1e-12f);
        if (node < N) {
#pragma unroll
            for (int f = 0; f < 4; ++f) {
                float r = fmaxf(hv[f] * sc, 0.f);
                unsigned short rb = f2bf(r);
                float e = bf2f(rb);
                mh[(size_t)node * 64 + f * 16 + l15] = rb;
                psum[f] += e;
                psq[f] += e * e;
            }
        }
    }

#pragma unroll
    for (int f = 0; f < 4; ++f) {
        psum[f] += __shfl_xor(psum[f], 16);
        psum[f] += __shfl_xor(psum[f], 32);
        psq[f] += __shfl_xor(psq[f], 16);
        psq[f] += __shfl_xor(psq[f], 32);
    }
    if (lane < 16) {
#pragma unroll
        for (int f = 0; f < 4; ++f) {
            sRed[wid][f * 16 + l15] = psum[f];
            sRed[wid][64 + f * 16 + l15] = psq[f];
        }
    }
    __syncthreads();
    if (tid < 128) {
        float v = sRed[0][tid] + sRed[1][tid] + sRed[2][tid] + sRed[3][tid];
        pstats[(size_t)blockIdx.x * 128 + tid] = v;
    }
}

// ---------------------------------------------- reduce per-block BN partials
__global__ __launch_bounds__(64) void k_stats(const float* __restrict__ pstats,
                                              float* __restrict__ stats, int nblk) {
    int col = blockIdx.x;
    int l = threadIdx.x;
    float s = 0.f;
    for (int r = l; r < nblk; r += 64) s += pstats[(size_t)r * 128 + col];
    s += __shfl_xor(s, 1);
    s += __shfl_xor(s, 2);
    s += __shfl_xor(s, 4);
    s += __shfl_xor(s, 8);
    s += __shfl_xor(s, 16);
    s += __shfl_xor(s, 32);
    if (l == 0) stats[col] = s;
}

// ---------------------------------------------------------------- BN-fold + FC
__global__ __launch_bounds__(256) void k_out(
        const unsigned short* __restrict__ h, const float* __restrict__ stats,
        const float* __restrict__ gamma, const float* __restrict__ beta,
        const float* __restrict__ Wfc, const float* __restrict__ bfc,
        float* __restrict__ out, int N) {
    __shared__ float sWm[64 * 16];
    __shared__ float sShift[64];
    __shared__ float sBase[16];
    const int tid = threadIdx.x;
    const float invN = 1.0f / (float)N;
    if (tid < 64) {
        float mu = stats[tid] * invN;
        float var = stats[64 + tid] * invN - mu * mu;
        float sc = gamma[tid] / sqrtf(var + 1e-5f);
        sShift[tid] = beta[tid] - mu * sc;
#pragma unroll
        for (int c = 0; c < 16; ++c) sWm[tid * 16 + c] = Wfc[c * 64 + tid] * sc;
    }
    __syncthreads();
    if (tid < 16) {
        float b = bfc[tid];
#pragma unroll
        for (int j = 0; j < 64; ++j) b += sShift[j] * Wfc[tid * 64 + j];
        sBase[tid] = b;
    }
    __syncthreads();
    int g = blockIdx.x * 256 + tid;
    int n = g >> 4;
    int c = g & 15;
    if (n >= N) return;
    const ushort4* h4 = (const ushort4*)(h + (size_t)n * 64);
    float acc = sBase[c];
#pragma unroll
    for (int jq = 0; jq < 16; ++jq) {
        ushort4 v = h4[jq];
        acc += bf2f(v.x) * sWm[(jq * 4 + 0) * 16 + c];
        acc += bf2f(v.y) * sWm[(jq * 4 + 1) * 16 + c];
        acc += bf2f(v.z) * sWm[(jq * 4 + 2) * 16 + c];
        acc += bf2f(v.w) * sWm[(jq * 4 + 3) * 16 + c];
    }
    out[(size_t)n * 16 + c] = acc;
}

extern "C" void kernel_launch(void* const* d_in, const int* in_sizes, int n_in,
                              void* d_out, int out_size, void* d_ws, size_t ws_size,
                              hipStream_t stream) {
    const int* eidx = (const int*)d_in[0];
    const float* x = (const float*)d_in[1];
    const float* Wl = (const float*)d_in[2];
    const float* bl = (const float*)d_in[3];
    const float* Wr = (const float*)d_in[4];
    const float* gamma = (const float*)d_in[5];
    const float* beta = (const float*)d_in[6];
    const float* Wfc = (const float*)d_in[7];
    const float* bfc = (const float*)d_in[8];
    float* out = (float*)d_out;

    const int E = in_sizes[0] / 2;
    const int N = in_sizes[1] / 64;
    const int fblocks = (N + 63) / 64;
    const int sblocks = (N + 1023) / 1024;

    // tiered layout: words(K, xbf) = K*N + N + (N+1) + E + E + N*32
    //                               + fblocks*128 + 128 + 256 [+ N*32]
    auto bytes_for = [&](int K, bool xb) -> size_t {
        size_t w = (size_t)K * N + N + (N + 1) + E + E + (size_t)N * 32 +
                   (size_t)fblocks * 128 + 128 + 256;
        if (xb) w += (size_t)N * 32;
        return w * 4;
    };
    int K;
    bool xbf_on;
    if (ws_size >= bytes_for(8, true)) { K = 8; xbf_on = true; }
    else if (ws_size >= bytes_for(8, false)) { K = 8; xbf_on = false; }
    else if (ws_size >= bytes_for(1, true)) { K = 1; xbf_on = true; }
    else { K = 1; xbf_on = false; }

    int* cnt = (int*)d_ws;                                     // K*N (zeroed)
    int* deg = cnt + (size_t)K * N;                            // N
    int* rowptr = deg + N;                                     // N+1
    int* colv = rowptr + (N + 1);                              // E
    int* rank = colv + E;                                      // E
    unsigned short* mh = (unsigned short*)(rank + E);          // N*64 bf16
    float* pstats = (float*)(mh + (size_t)N * 64);             // fblocks*128
    float* stats = pstats + (size_t)fblocks * 128;             // 128
    int* bsum = (int*)(stats + 128);                           // 256
    unsigned short* xbf = (unsigned short*)(bsum + 256);       // N*64 bf16

    hipMemsetAsync(d_ws, 0, (size_t)K * N * 4, stream);

    int eblocks = (E + 255) / 256;
    int nblocks = (N + 255) / 256;
    k_histrank<<<eblocks, 256, 0, stream>>>(eidx, cnt, rank, E, N, K);
    k_deg<<<nblocks, 256, 0, stream>>>(cnt, deg, N, K);
    k_scan1<<<sblocks, 256, 0, stream>>>(deg, rowptr, bsum, N);
    k_scan2<<<1, 256, 0, stream>>>(bsum, sblocks);
    k_scan3<<<sblocks, 256, 0, stream>>>(rowptr, bsum, N, E);
    k_fill<<<eblocks, 256, 0, stream>>>(eidx, rowptr, cnt, rank, colv, E, N, K);

    int gblocks = (int)(((size_t)N * 16 + 255) / 256);
    if (xbf_on) {
        k_xcast<<<gblocks, 256, 0, stream>>>((const float4*)x, (ushort4*)xbf, N * 16);
        k_gather_bf<<<gblocks, 256, 0, stream>>>((const ushort4*)xbf, rowptr, colv,
                                                 (ushort4*)mh, N);
    } else {
        k_gather_f32<<<gblocks, 256, 0, stream>>>((const float4*)x, rowptr, colv,
                                                  (ushort4*)mh, N);
    }

    k_fused<<<fblocks, 256, 0, stream>>>(x, Wl, bl, Wr, mh, pstats, N);

    k_stats<<<128, 64, 0, stream>>>(pstats, stats, fblocks);

    int oblocks = (int)(((size_t)N * 16 + 255) / 256);
    k_out<<<oblocks, 256, 0, stream>>>(mh, stats, gamma, beta, Wfc, bfc, out, N);
}

// Round 9
// 235.972 us; speedup vs baseline: 1.1404x; 1.1404x over previous
//
#include <hip/hip_runtime.h>
#include <hip/hip_bf16.h>

// SAGEConv(mean): atomic-free CSR build (two-level bucket counting sort, LDS
// atomics only) + bf16 gather + MFMA fused [mean|x]@[Wl;Wr]^T + L2norm + ReLU
// + BN-partials + stats-reduce + BN-fold FC.  N=100000, E=1200000, F=H=64, C=16.
//
// Lessons: R4 same-address f32 atomics = ~600us. R5 per-edge cursor atomics
// = 99us. R7/R8 device-scope atomics execute at the shared coherence point
// (memory-side): ~24.5 G atomics/s, ~32B sector per op, XCD privatization is
// useless. Fix: NO global atomics anywhere — bucket sort with LDS counters.
//
// Buckets: b = dst >> 9 (512 nodes/bucket, NB = ceil(N/512) <= 256).
// Pack (dst&511)<<17 | src into 4B (valid for N <= 131072).
//
// ws layout (4B words): [colv: E][rowptr: N+1][cnt: NBLK*NB][btot: 256]
//   [bbase: 257][pstats: fblocks*128][stats: 128][mh: N*32]
//   then tail: xbf_on ? [xbf: N*32 with ebuf(E) aliased at its start]
//                     : [ebuf: E]

typedef __attribute__((ext_vector_type(8))) short short8;   // 8 bf16
typedef __attribute__((ext_vector_type(4))) float f32x4;

__device__ __forceinline__ unsigned short f2bf(float f) {
    unsigned int u = __builtin_bit_cast(unsigned int, f);
    u += 0x7FFFu + ((u >> 16) & 1u);
    return (unsigned short)(u >> 16);
}
__device__ __forceinline__ float bf2f(unsigned short s) {
    return __builtin_bit_cast(float, ((unsigned int)s) << 16);
}

#define CHUNK 8192

// ---------------- pass A: per-(block,bucket) histogram via LDS atomics
__global__ __launch_bounds__(256) void k_bhist(const int* __restrict__ eidx,
                                               int* __restrict__ cnt,
                                               int E, int NB) {
    __shared__ int lh[256];
    const int tid = threadIdx.x;
    lh[tid] = 0;
    __syncthreads();
    const int base = blockIdx.x * CHUNK;
    for (int i = tid; i < CHUNK; i += 256) {
        int e = base + i;
        if (e < E) atomicAdd(&lh[eidx[E + e] >> 9], 1);
    }
    __syncthreads();
    if (tid < NB) cnt[(size_t)blockIdx.x * NB + tid] = lh[tid];
}

// ---------------- pass B1: per-bucket column scan over blocks (in-place excl)
__global__ __launch_bounds__(256) void k_bscanA(int* __restrict__ cnt,
                                                int* __restrict__ btot,
                                                int NBLK, int NB) {
    __shared__ int swv[4];
    const int b = blockIdx.x;
    const int t = threadIdx.x;
    int v = (t < NBLK) ? cnt[(size_t)t * NB + b] : 0;
    const int lane = t & 63, wid = t >> 6;
    int s = v;
#pragma unroll
    for (int off = 1; off < 64; off <<= 1) {
        int tt = __shfl_up(s, off);
        if (lane >= off) s += tt;
    }
    if (lane == 63) swv[wid] = s;
    __syncthreads();
    if (t == 0) {
        int a = 0;
#pragma unroll
        for (int w = 0; w < 4; ++w) { int tt = swv[w]; swv[w] = a; a += tt; }
    }
    __syncthreads();
    int excl = s - v + swv[wid];
    if (t < NBLK) cnt[(size_t)t * NB + b] = excl;
    if (t == NBLK - 1) btot[b] = excl + v;
}

// ---------------- pass B2: scan bucket totals -> bbase; finalize sentinels
__global__ __launch_bounds__(256) void k_bscanB(const int* __restrict__ btot,
                                                int* __restrict__ bbase,
                                                int* __restrict__ rowptr,
                                                int NB, int N, int E) {
    __shared__ int swv[4];
    const int t = threadIdx.x;
    int v = (t < NB) ? btot[t] : 0;
    const int lane = t & 63, wid = t >> 6;
    int s = v;
#pragma unroll
    for (int off = 1; off < 64; off <<= 1) {
        int tt = __shfl_up(s, off);
        if (lane >= off) s += tt;
    }
    if (lane == 63) swv[wid] = s;
    __syncthreads();
    if (t == 0) {
        int a = 0;
#pragma unroll
        for (int w = 0; w < 4; ++w) { int tt = swv[w]; swv[w] = a; a += tt; }
    }
    __syncthreads();
    if (t < NB) bbase[t] = s - v + swv[wid];
    if (t == 0) { bbase[NB] = E; rowptr[N] = E; }
}

// ---------------- pass C: scatter packed edges into bucket segments
__global__ __launch_bounds__(256) void k_bscatter(const int* __restrict__ eidx,
                                                  const int* __restrict__ cnt,
                                                  const int* __restrict__ bbase,
                                                  unsigned int* __restrict__ ebuf,
                                                  int E, int NB) {
    __shared__ int cur[256];
    const int tid = threadIdx.x;
    if (tid < NB) cur[tid] = bbase[tid] + cnt[(size_t)blockIdx.x * NB + tid];
    __syncthreads();
    const int base = blockIdx.x * CHUNK;
    for (int i = tid; i < CHUNK; i += 256) {
        int e = base + i;
        if (e < E) {
            int d = eidx[E + e];
            int s = eidx[e];
            int p = atomicAdd(&cur[d >> 9], 1);
            ebuf[p] = (unsigned int)s | ((unsigned int)(d & 511) << 17);
        }
    }
}

// ---------------- pass D: per-bucket LDS hist + scan -> rowptr + colv
__global__ __launch_bounds__(256) void k_bfinal(const unsigned int* __restrict__ ebuf,
                                                const int* __restrict__ bbase,
                                                int* __restrict__ rowptr,
                                                int* __restrict__ colv, int N) {
    __shared__ int h[512];
    __shared__ int swv[4];
    const int b = blockIdx.x;
    const int tid = threadIdx.x;
    h[2 * tid] = 0;
    h[2 * tid + 1] = 0;
    __syncthreads();
    const int segb = bbase[b], sege = bbase[b + 1];
    for (int i = segb + tid; i < sege; i += 256)
        atomicAdd(&h[ebuf[i] >> 17], 1);
    __syncthreads();
    // exclusive scan over 512 counters (2/thread)
    int a0 = h[2 * tid], a1 = h[2 * tid + 1];
    int ts = a0 + a1;
    const int lane = tid & 63, wid = tid >> 6;
    int s = ts;
#pragma unroll
    for (int off = 1; off < 64; off <<= 1) {
        int tt = __shfl_up(s, off);
        if (lane >= off) s += tt;
    }
    if (lane == 63) swv[wid] = s;
    __syncthreads();
    if (tid == 0) {
        int a = 0;
#pragma unroll
        for (int w = 0; w < 4; ++w) { int tt = swv[w]; swv[w] = a; a += tt; }
    }
    __syncthreads();
    int excl = s - ts + swv[wid];
    h[2 * tid] = excl;
    h[2 * tid + 1] = excl + a0;
    int node = b * 512 + 2 * tid;
    if (node < N) rowptr[node] = segb + excl;
    if (node + 1 < N) rowptr[node + 1] = segb + excl + a0;
    __syncthreads();
    for (int i = segb + tid; i < sege; i += 256) {
        unsigned int u = ebuf[i];
        int p = atomicAdd(&h[u >> 17], 1);
        colv[segb + p] = (int)(u & 0x1FFFFu);
    }
}

// ---------------------------------------------------------------- x -> bf16
__global__ __launch_bounds__(256) void k_xcast(const float4* __restrict__ x4,
                                               ushort4* __restrict__ xbf, int n4) {
    int t = blockIdx.x * 256 + threadIdx.x;
    if (t < n4) {
        float4 v = x4[t];
        xbf[t] = make_ushort4(f2bf(v.x), f2bf(v.y), f2bf(v.z), f2bf(v.w));
    }
}

// -------------- gather-mean (bf16 x): 8 lanes/node, 16B loads, full occupancy
__global__ __launch_bounds__(256) void k_gather_bf(
        const uint4* __restrict__ xbf8, const int* __restrict__ rowptr,
        const int* __restrict__ colv, uint4* __restrict__ mh8, int N) {
    int t = blockIdx.x * 256 + threadIdx.x;
    int n = t >> 3;
    int l = t & 7;
    if (n >= N) return;
    int b = rowptr[n], e = rowptr[n + 1];
    float a[8] = {0.f, 0.f, 0.f, 0.f, 0.f, 0.f, 0.f, 0.f};
    int p = b;
    for (; p + 4 <= e; p += 4) {
        int s0 = colv[p], s1 = colv[p + 1], s2 = colv[p + 2], s3 = colv[p + 3];
        uint4 v0 = xbf8[(size_t)s0 * 8 + l];
        uint4 v1 = xbf8[(size_t)s1 * 8 + l];
        uint4 v2 = xbf8[(size_t)s2 * 8 + l];
        uint4 v3 = xbf8[(size_t)s3 * 8 + l];
        unsigned int w0[4] = {v0.x, v0.y, v0.z, v0.w};
        unsigned int w1[4] = {v1.x, v1.y, v1.z, v1.w};
        unsigned int w2[4] = {v2.x, v2.y, v2.z, v2.w};
        unsigned int w3[4] = {v3.x, v3.y, v3.z, v3.w};
#pragma unroll
        for (int q = 0; q < 4; ++q) {
            a[2 * q] += bf2f((unsigned short)(w0[q] & 0xFFFF)) +
                        bf2f((unsigned short)(w1[q] & 0xFFFF)) +
                        bf2f((unsigned short)(w2[q] & 0xFFFF)) +
                        bf2f((unsigned short)(w3[q] & 0xFFFF));
            a[2 * q + 1] += bf2f((unsigned short)(w0[q] >> 16)) +
                            bf2f((unsigned short)(w1[q] >> 16)) +
                            bf2f((unsigned short)(w2[q] >> 16)) +
                            bf2f((unsigned short)(w3[q] >> 16));
        }
    }
    for (; p < e; ++p) {
        int s0 = colv[p];
        uint4 v0 = xbf8[(size_t)s0 * 8 + l];
        unsigned int w0[4] = {v0.x, v0.y, v0.z, v0.w};
#pragma unroll
        for (int q = 0; q < 4; ++q) {
            a[2 * q] += bf2f((unsigned short)(w0[q] & 0xFFFF));
            a[2 * q + 1] += bf2f((unsigned short)(w0[q] >> 16));
        }
    }
    float inv = 1.0f / fmaxf((float)(e - b), 1.0f);
    uint4 o;
    unsigned int* op = &o.x;
#pragma unroll
    for (int q = 0; q < 4; ++q) {
        unsigned int lo = f2bf(a[2 * q] * inv);
        unsigned int hi = f2bf(a[2 * q + 1] * inv);
        op[q] = lo | (hi << 16);
    }
    mh8[(size_t)n * 8 + l] = o;
}

// ------------------------- gather-mean (f32 x fallback, if ws too small)
__global__ __launch_bounds__(256) void k_gather_f32(
        const float4* __restrict__ x4, const int* __restrict__ rowptr,
        const int* __restrict__ colv, ushort4* __restrict__ mh, int N) {
    int t = blockIdx.x * 256 + threadIdx.x;
    int n = t >> 4;
    int l = t & 15;
    if (n >= N) return;
    int b = rowptr[n], e = rowptr[n + 1];
    float ax = 0.f, ay = 0.f, az = 0.f, aw = 0.f;
    int p = b;
    for (; p + 4 <= e; p += 4) {
        int s0 = colv[p], s1 = colv[p + 1], s2 = colv[p + 2], s3 = colv[p + 3];
        float4 v0 = x4[(size_t)s0 * 16 + l];
        float4 v1 = x4[(size_t)s1 * 16 + l];
        float4 v2 = x4[(size_t)s2 * 16 + l];
        float4 v3 = x4[(size_t)s3 * 16 + l];
        ax += (v0.x + v1.x) + (v2.x + v3.x);
        ay += (v0.y + v1.y) + (v2.y + v3.y);
        az += (v0.z + v1.z) + (v2.z + v3.z);
        aw += (v0.w + v1.w) + (v2.w + v3.w);
    }
    for (; p < e; ++p) {
        int s0 = colv[p];
        float4 v0 = x4[(size_t)s0 * 16 + l];
        ax += v0.x; ay += v0.y; az += v0.z; aw += v0.w;
    }
    float inv = 1.0f / fmaxf((float)(e - b), 1.0f);
    mh[(size_t)n * 16 + l] = make_ushort4(f2bf(ax * inv), f2bf(ay * inv),
                                          f2bf(az * inv), f2bf(aw * inv));
}

// --------- fused MFMA: [mean|x]@[Wl;Wr]^T + bl, L2norm, ReLU, BN partials.
__global__ __launch_bounds__(256) void k_fused(
        const float* __restrict__ x,
        const float* __restrict__ Wl, const float* __restrict__ bl,
        const float* __restrict__ Wr,
        unsigned short* __restrict__ mh,   // in: bf16 mean; out: bf16 h
        float* __restrict__ pstats, int N) {
    __shared__ float sRed[4][128];

    const int tid = threadIdx.x;
    const int wid = tid >> 6;
    const int lane = tid & 63;
    const int l15 = lane & 15;
    const int quad = lane >> 4;
    const int tbase = blockIdx.x * 64 + wid * 16;

    short8 bfrag[4][4];
#pragma unroll
    for (int c = 0; c < 4; ++c) {
#pragma unroll
        for (int f = 0; f < 4; ++f) {
            const int n = f * 16 + l15;
            const float* wsrc = (c < 2)
                ? (Wl + (size_t)n * 64 + c * 32 + quad * 8)
                : (Wr + (size_t)n * 64 + (c - 2) * 32 + quad * 8);
            float4 w0 = *(const float4*)wsrc;
            float4 w1 = *(const float4*)(wsrc + 4);
            union { short8 v; unsigned short u[8]; } pk;
            pk.u[0] = f2bf(w0.x); pk.u[1] = f2bf(w0.y);
            pk.u[2] = f2bf(w0.z); pk.u[3] = f2bf(w0.w);
            pk.u[4] = f2bf(w1.x); pk.u[5] = f2bf(w1.y);
            pk.u[6] = f2bf(w1.z); pk.u[7] = f2bf(w1.w);
            bfrag[c][f] = pk.v;
        }
    }

    const int mrow = tbase + l15;
    const int mld = (mrow < N) ? mrow : (N - 1);
    f32x4 acc[4] = {{0.f, 0.f, 0.f, 0.f}, {0.f, 0.f, 0.f, 0.f},
                    {0.f, 0.f, 0.f, 0.f}, {0.f, 0.f, 0.f, 0.f}};
#pragma unroll
    for (int c = 0; c < 2; ++c) {
        short8 a = *(const short8*)(mh + (size_t)mld * 64 + c * 32 + quad * 8);
#pragma unroll
        for (int f = 0; f < 4; ++f)
            acc[f] = __builtin_amdgcn_mfma_f32_16x16x32_bf16(a, bfrag[c][f], acc[f], 0, 0, 0);
    }
#pragma unroll
    for (int c = 2; c < 4; ++c) {
        const float* xp = x + (size_t)mld * 64 + (c - 2) * 32 + quad * 8;
        float4 a0 = *(const float4*)xp;
        float4 a1 = *(const float4*)(xp + 4);
        union { short8 v; unsigned short u[8]; } pk;
        pk.u[0] = f2bf(a0.x); pk.u[1] = f2bf(a0.y);
        pk.u[2] = f2bf(a0.z); pk.u[3] = f2bf(a0.w);
        pk.u[4] = f2bf(a1.x); pk.u[5] = f2bf(a1.y);
        pk.u[6] = f2bf(a1.z); pk.u[7] = f2bf(a1.w);
#pragma unroll
        for (int f = 0; f < 4; ++f)
            acc[f] = __builtin_amdgcn_mfma_f32_16x16x32_bf16(pk.v, bfrag[c][f], acc[f], 0, 0, 0);
    }

    float blv[4];
#pragma unroll
    for (int f = 0; f < 4; ++f) blv[f] = bl[f * 16 + l15];

    float psum[4] = {0.f, 0.f, 0.f, 0.f};
    float psq[4] = {0.f, 0.f, 0.f, 0.f};
#pragma unroll
    for (int reg = 0; reg < 4; ++reg) {
        const int node = tbase + quad * 4 + reg;
        float hv[4];
        float ss = 0.f;
#pragma unroll
        for (int f = 0; f < 4; ++f) {
            hv[f] = acc[f][reg] + blv[f];
            ss += hv[f] * hv[f];
        }
        ss += __shfl_xor(ss, 1);
        ss += __shfl_xor(ss, 2);
        ss += __shfl_xor(ss, 4);
        ss += __shfl_xor(ss, 8);
        float sc = 1.0f / fmaxf(sqrtf(ss), 1e-12f);
        if (node < N) {
#pragma unroll
            for (int f = 0; f < 4; ++f) {
                float r = fmaxf(hv[f] * sc, 0.f);
                unsigned short rb = f2bf(r);
                float e = bf2f(rb);
                mh[(size_t)node * 64 + f * 16 + l15] = rb;
                psum[f] += e;
                psq[f] += e * e;
            }
        }
    }

#pragma unroll
    for (int f = 0; f < 4; ++f) {
        psum[f] += __shfl_xor(psum[f], 16);
        psum[f] += __shfl_xor(psum[f], 32);
        psq[f] += __shfl_xor(psq[f], 16);
        psq[f] += __shfl_xor(psq[f], 32);
    }
    if (lane < 16) {
#pragma unroll
        for (int f = 0; f < 4; ++f) {
            sRed[wid][f * 16 + l15] = psum[f];
            sRed[wid][64 + f * 16 + l15] = psq[f];
        }
    }
    __syncthreads();
    if (tid < 128) {
        float v = sRed[0][tid] + sRed[1][tid] + sRed[2][tid] + sRed[3][tid];
        pstats[(size_t)blockIdx.x * 128 + tid] = v;
    }
}

// ---------------------------------------------- reduce per-block BN partials
__global__ __launch_bounds__(64) void k_stats(const float* __restrict__ pstats,
                                              float* __restrict__ stats, int nblk) {
    int col = blockIdx.x;
    int l = threadIdx.x;
    float s = 0.f;
    for (int r = l; r < nblk; r += 64) s += pstats[(size_t)r * 128 + col];
    s += __shfl_xor(s, 1);
    s += __shfl_xor(s, 2);
    s += __shfl_xor(s, 4);
    s += __shfl_xor(s, 8);
    s += __shfl_xor(s, 16);
    s += __shfl_xor(s, 32);
    if (l == 0) stats[col] = s;
}

// ---------------------------------------------------------------- BN-fold + FC
__global__ __launch_bounds__(256) void k_out(
        const unsigned short* __restrict__ h, const float* __restrict__ stats,
        const float* __restrict__ gamma, const float* __restrict__ beta,
        const float* __restrict__ Wfc, const float* __restrict__ bfc,
        float* __restrict__ out, int N) {
    __shared__ float sWm[64 * 16];
    __shared__ float sShift[64];
    __shared__ float sBase[16];
    const int tid = threadIdx.x;
    const float invN = 1.0f / (float)N;
    if (tid < 64) {
        float mu = stats[tid] * invN;
        float var = stats[64 + tid] * invN - mu * mu;
        float sc = gamma[tid] / sqrtf(var + 1e-5f);
        sShift[tid] = beta[tid] - mu * sc;
#pragma unroll
        for (int c = 0; c < 16; ++c) sWm[tid * 16 + c] = Wfc[c * 64 + tid] * sc;
    }
    __syncthreads();
    if (tid < 16) {
        float b = bfc[tid];
#pragma unroll
        for (int j = 0; j < 64; ++j) b += sShift[j] * Wfc[tid * 64 + j];
        sBase[tid] = b;
    }
    __syncthreads();
    int g = blockIdx.x * 256 + tid;
    int n = g >> 4;
    int c = g & 15;
    if (n >= N) return;
    const ushort4* h4 = (const ushort4*)(h + (size_t)n * 64);
    float acc = sBase[c];
#pragma unroll
    for (int jq = 0; jq < 16; ++jq) {
        ushort4 v = h4[jq];
        acc += bf2f(v.x) * sWm[(jq * 4 + 0) * 16 + c];
        acc += bf2f(v.y) * sWm[(jq * 4 + 1) * 16 + c];
        acc += bf2f(v.z) * sWm[(jq * 4 + 2) * 16 + c];
        acc += bf2f(v.w) * sWm[(jq * 4 + 3) * 16 + c];
    }
    out[(size_t)n * 16 + c] = acc;
}

extern "C" void kernel_launch(void* const* d_in, const int* in_sizes, int n_in,
                              void* d_out, int out_size, void* d_ws, size_t ws_size,
                              hipStream_t stream) {
    const int* eidx = (const int*)d_in[0];
    const float* x = (const float*)d_in[1];
    const float* Wl = (const float*)d_in[2];
    const float* bl = (const float*)d_in[3];
    const float* Wr = (const float*)d_in[4];
    const float* gamma = (const float*)d_in[5];
    const float* beta = (const float*)d_in[6];
    const float* Wfc = (const float*)d_in[7];
    const float* bfc = (const float*)d_in[8];
    float* out = (float*)d_out;

    const int E = in_sizes[0] / 2;
    const int N = in_sizes[1] / 64;
    const int fblocks = (N + 63) / 64;
    const int NB = (N + 511) >> 9;                 // buckets (<=256 for N<=131072)
    const int NBLK = (E + CHUNK - 1) / CHUNK;      // <=256 for E<=2.1M

    // fixed region
    int* colv = (int*)d_ws;                                    // E
    int* rowptr = colv + E;                                    // N+1
    int* cnt = rowptr + (N + 1);                               // NBLK*NB
    int* btot = cnt + (size_t)NBLK * NB;                       // 256
    int* bbase = btot + 256;                                   // 257
    float* pstats = (float*)(bbase + 257);                     // fblocks*128
    float* stats = pstats + (size_t)fblocks * 128;             // 128
    unsigned short* mh = (unsigned short*)(stats + 128);       // N*64 bf16
    unsigned int* tail = (unsigned int*)(mh + (size_t)N * 64);

    // tail: xbf (N*32 words) with ebuf aliased at its start, or ebuf alone
    size_t fixed_words = (size_t)(tail - (unsigned int*)d_ws);
    const bool xbf_on = (ws_size >= (fixed_words + (size_t)N * 32) * 4);
    unsigned short* xbf = (unsigned short*)tail;
    unsigned int* ebuf = tail;   // dead before xcast writes xbf (in-order stream)

    int eblocks = (E + 255) / 256;
    k_bhist<<<NBLK, 256, 0, stream>>>(eidx, cnt, E, NB);
    k_bscanA<<<NB, 256, 0, stream>>>(cnt, btot, NBLK, NB);
    k_bscanB<<<1, 256, 0, stream>>>(btot, bbase, rowptr, NB, N, E);
    k_bscatter<<<NBLK, 256, 0, stream>>>(eidx, cnt, bbase, ebuf, E, NB);
    k_bfinal<<<NB, 256, 0, stream>>>(ebuf, bbase, rowptr, colv, N);

    if (xbf_on) {
        int cblocks = (int)(((size_t)N * 16 + 255) / 256);
        k_xcast<<<cblocks, 256, 0, stream>>>((const float4*)x, (ushort4*)xbf, N * 16);
        int gblocks = (int)(((size_t)N * 8 + 255) / 256);
        k_gather_bf<<<gblocks, 256, 0, stream>>>((const uint4*)xbf, rowptr, colv,
                                                 (uint4*)mh, N);
    } else {
        int gblocks = (int)(((size_t)N * 16 + 255) / 256);
        k_gather_f32<<<gblocks, 256, 0, stream>>>((const float4*)x, rowptr, colv,
                                                  (ushort4*)mh, N);
    }

    k_fused<<<fblocks, 256, 0, stream>>>(x, Wl, bl, Wr, mh, pstats, N);

    k_stats<<<128, 64, 0, stream>>>(pstats, stats, fblocks);

    int oblocks = (int)(((size_t)N * 16 + 255) / 256);
    k_out<<<oblocks, 256, 0, stream>>>(mh, stats, gamma, beta, Wfc, bfc, out, N);
}